// Round 2
// baseline (261.782 us; speedup 1.0000x reference)
//
#include <hip/hip_runtime.h>

#define HDIM  256
#define YP    264              // padded Y row length in bf16 elems
#define SPBM  8                // samples per block
#define MROWS (SPBM * 8)       // 64 jet rows per block

typedef unsigned short u16;
typedef __attribute__((ext_vector_type(8))) short  short8;   // 8 bf16 (4 VGPRs)
typedef __attribute__((ext_vector_type(4))) float  f32x4;    // MFMA acc

__device__ __forceinline__ float bf2f(u16 u) {
    union { unsigned int i; float f; } v; v.i = ((unsigned int)u) << 16; return v.f;
}
// cheap round-half-up bf16 (2 VALU instr); fine vs 3% abs threshold
__device__ __forceinline__ u16 f2bf(float f) {
    union { float f; unsigned int u; } v; v.f = f;
    return (u16)((v.u + 0x8000u) >> 16);
}
// proper RNE, used once in prepass for weights
__device__ __forceinline__ u16 f2bf_rne(float f) {
    union { float f; unsigned int u; } v; v.f = f;
    unsigned int r = v.u + 0x7fffu + ((v.u >> 16) & 1u);
    return (u16)(r >> 16);
}
// tanh(x) = 1 - 2/(e^{2x}+1) on raw v_exp_f32 / v_rcp_f32 (~4 instr, NaN-free)
__device__ __forceinline__ float fast_tanh(float x) {
    const float e = __builtin_amdgcn_exp2f(x * 2.885390081777927f); // e^{2x}
    const float r = __builtin_amdgcn_rcpf(e + 1.f);
    return 1.f - 2.f * r;
}

// ---- prepass: LDS-tiled transpose W[k][n] f32 -> Wt[n][k] bf16 (W1,W2,W3),
// ---- plus Wo[k][2] -> Wob[2][256] bf16 at ws + 3*65536.
// 97 blocks (32k x 64n tiles, 32 per matrix).
__global__ __launch_bounds__(256)
void prep_w(const float* __restrict__ W1, const float* __restrict__ W2,
            const float* __restrict__ W3, const float* __restrict__ Wo,
            u16* __restrict__ ws) {
    const int bid = blockIdx.x;
    const int tid = threadIdx.x;
    if (bid == 96) {
#pragma unroll
        for (int oc = 0; oc < 2; ++oc)
            ws[3 * 65536 + oc * 256 + tid] = f2bf_rne(Wo[tid * 2 + oc]);
        return;
    }
    const int which = bid >> 5;          // 0..2
    const int tile  = bid & 31;          // 32 tiles: 8 k-tiles x 4 n-tiles
    const int k0 = (tile & 7) * 32;
    const int n0 = (tile >> 3) * 64;
    const float* W = (which == 0) ? W1 : ((which == 1) ? W2 : W3);
    __shared__ float T[32][65];
    const int rk = tid >> 4;             // 0..15
    const int rn = (tid & 15) * 4;       // 0..60
#pragma unroll
    for (int rep = 0; rep < 2; ++rep) {
        const float4 v = *(const float4*)(W + (k0 + rep * 16 + rk) * 256 + n0 + rn);
        T[rep * 16 + rk][rn + 0] = v.x;
        T[rep * 16 + rk][rn + 1] = v.y;
        T[rep * 16 + rk][rn + 2] = v.z;
        T[rep * 16 + rk][rn + 3] = v.w;
    }
    __syncthreads();
    const int wn = tid >> 2;             // 0..63
    const int wk = (tid & 3) * 8;        // 0,8,16,24
    short8 o;
#pragma unroll
    for (int i = 0; i < 8; ++i)
        o[i] = (short)f2bf_rne(T[wk + i][wn]);
    *(short8*)(ws + which * 65536 + (n0 + wn) * 256 + k0 + wk) = o;
}

// ---- one hidden layer: Y(LDS, 64x256 bf16 jets) @ W(256x256) -> jets, in place ----
// 8 waves: wave wv owns a 32x64 slice: rows (wv>>2)*32..+31, cols (wv&3)*64..+63.
// acc = 2x4 f32x4 = 32 VGPRs (vs 64 in the 4-wave version) -> 2 blocks/CU resident.
// C/D: col=lane&15, row=(lane>>4)*4+reg.  A: A[m=lane&15][k=8*(lane>>4)+j].
// Channel rows per sample: 0=v 1=g0 2=g1 3=g2 | 4=g3 5=s0 6=s1 7=s2 -> lane L pairs L^16.
__device__ __forceinline__ void hidden_layer_mfma(u16* __restrict__ Y,
                                                  const u16* __restrict__ Wt,
                                                  const float* __restrict__ b,
                                                  int l, int wv) {
    const int lm    = l & 15;
    const int lk8   = (l >> 4) * 8;
    const int mh    = (wv >> 2) * 32;    // row base of this wave's half
    const int nbase = (wv & 3) * 64;     // col base of this wave's quarter

    f32x4 acc[2][4];
#pragma unroll
    for (int mt = 0; mt < 2; ++mt)
#pragma unroll
        for (int nt = 0; nt < 4; ++nt) acc[mt][nt] = (f32x4){0.f, 0.f, 0.f, 0.f};

#pragma unroll
    for (int ks = 0; ks < 8; ++ks) {
        const int kk = ks * 32 + lk8;
        short8 a[2], bf[4];
#pragma unroll
        for (int mt = 0; mt < 2; ++mt)
            a[mt] = *(const short8*)(Y + (mh + mt * 16 + lm) * YP + kk);
#pragma unroll
        for (int nt = 0; nt < 4; ++nt)
            bf[nt] = *(const short8*)(Wt + ((nbase + nt * 16 + lm) << 8) + kk);
#pragma unroll
        for (int mt = 0; mt < 2; ++mt)
#pragma unroll
            for (int nt = 0; nt < 4; ++nt)
                acc[mt][nt] = __builtin_amdgcn_mfma_f32_16x16x32_bf16(
                    a[mt], bf[nt], acc[mt][nt], 0, 0, 0);
    }

    float bias[4];
#pragma unroll
    for (int nt = 0; nt < 4; ++nt) bias[nt] = b[nbase + nt * 16 + lm];

    __syncthreads();   // all waves done READING Y before anyone overwrites it

    const int hi = (l >> 4) & 1;      // 0: rows v,g0,g1,g2   1: rows g3,s0,s1,s2
#pragma unroll
    for (int mt = 0; mt < 2; ++mt) {
        const int r0 = mh + mt * 16 + (l >> 4) * 4;
#pragma unroll
        for (int nt = 0; nt < 4; ++nt) {
            const f32x4 u = acc[mt][nt];
            const float ty  = fast_tanh(u[0] + bias[nt]);  // meaningful on hi==0 lanes
            const float typ = __shfl_xor(ty,  16);
            const float p1  = __shfl_xor(u[1], 16);        // partner's g preacts
            const float p2  = __shfl_xor(u[2], 16);
            const float p3  = __shfl_xor(u[3], 16);
            const float tv = hi ? typ : ty;
            const float t  = 1.f - tv * tv;
            const float m  = -2.f * tv * t;
            const float o0 = hi ? t * u[0] : tv;                    // g3 | v
            const float o1 = t * u[1] + (hi ? m * p1 * p1 : 0.f);   // s0 | g0
            const float o2 = t * u[2] + (hi ? m * p2 * p2 : 0.f);   // s1 | g1
            const float o3 = t * u[3] + (hi ? m * p3 * p3 : 0.f);   // s2 | g2
            const int n = nbase + nt * 16 + lm;
            Y[(r0 + 0) * YP + n] = f2bf(o0);
            Y[(r0 + 1) * YP + n] = f2bf(o1);
            Y[(r0 + 2) * YP + n] = f2bf(o2);
            Y[(r0 + 3) * YP + n] = f2bf(o3);
        }
    }
    __syncthreads();
}

__global__ __launch_bounds__(512, 4)
void mlp_jet_mfma(const float* __restrict__ x,
                  const float* __restrict__ W0, const float* __restrict__ b0,
                  const float* __restrict__ b1, const float* __restrict__ b2,
                  const float* __restrict__ b3, const float* __restrict__ bo,
                  const u16* __restrict__ Wt,   // 3 x Wt[n][k] bf16, + Wob[2][256]
                  float* __restrict__ out, int nB) {
    __shared__ __align__(16) u16 Y[MROWS * YP];
    __shared__ float4 xs4[SPBM];
    __shared__ float  part[MROWS][2];

    const int tid = threadIdx.x;
    const int wv  = tid >> 6;            // 0..7
    const int l   = tid & 63;
    const int lm  = l & 15;
    const int lk8 = (l >> 4) * 8;
    const int n0  = blockIdx.x * SPBM;

    // ---- layer 0: 4 -> 256, VALU. 512 threads: tid>>8 picks sample half ----
    if (tid < SPBM) xs4[tid] = *(const float4*)(x + (n0 + tid) * 4);
    __syncthreads();
    {
        const int n  = tid & 255;
        const int s0 = (tid >> 8) * 4;
        const float w0 = W0[0 * HDIM + n], w1 = W0[1 * HDIM + n];
        const float w2 = W0[2 * HDIM + n], w3 = W0[3 * HDIM + n];
        const float bb = b0[n];
#pragma unroll
        for (int s = s0; s < s0 + 4; ++s) {
            const float4 xv = xs4[s];
            const float u  = xv.x * w0 + xv.y * w1 + xv.z * w2 + xv.w * w3 + bb;
            const float ty = fast_tanh(u);
            const float t  = 1.f - ty * ty;
            const float m  = -2.f * ty * t;
            u16* yr = Y + (8 * s) * YP + n;
            yr[0 * YP] = f2bf(ty);
            yr[1 * YP] = f2bf(t * w0);
            yr[2 * YP] = f2bf(t * w1);
            yr[3 * YP] = f2bf(t * w2);
            yr[4 * YP] = f2bf(t * w3);
            yr[5 * YP] = f2bf(m * w0 * w0);
            yr[6 * YP] = f2bf(m * w1 * w1);
            yr[7 * YP] = f2bf(m * w2 * w2);
        }
    }
    __syncthreads();

    // ---- 3 hidden layers on the matrix pipe ----
    hidden_layer_mfma(Y, Wt + 0 * 65536, b1, l, wv);
    hidden_layer_mfma(Y, Wt + 1 * 65536, b2, l, wv);
    hidden_layer_mfma(Y, Wt + 2 * 65536, b3, l, wv);

    // ---- output head on MFMA: waves 0..3 take rows wv*16..wv*16+15 ----
    if (wv < 4) {
        const u16* wob = Wt + 3 * 65536;
        f32x4 h = (f32x4){0.f, 0.f, 0.f, 0.f};
#pragma unroll
        for (int ks = 0; ks < 8; ++ks) {
            const int kk = ks * 32 + lk8;
            const short8 a = *(const short8*)(Y + (wv * 16 + lm) * YP + kk);
            short8 bfr = (short8){0,0,0,0,0,0,0,0};
            if (lm < 2) bfr = *(const short8*)(wob + lm * 256 + kk);
            h = __builtin_amdgcn_mfma_f32_16x16x32_bf16(a, bfr, h, 0, 0, 0);
        }
        if (lm < 2) {
#pragma unroll
            for (int r = 0; r < 4; ++r)
                part[wv * 16 + (l >> 4) * 4 + r][lm] = h[r];
        }
    }
    __syncthreads();

    if (tid < SPBM) {
        const int s = tid;
        float q0[8], q1[8];
#pragma unroll
        for (int ch = 0; ch < 8; ++ch) {
            q0[ch] = part[8 * s + ch][0];
            q1[ch] = part[8 * s + ch][1];
        }
        const float c0  = q0[0] + bo[0];
        const float Fi  = q1[0] + bo[1];
        const float cg0 = q0[1], cg1 = q0[2], cg2 = q0[3];
        const float ct  = q0[4];                 // dc/dx_3 (TDIM)
        const float fg0 = q1[1], fg1 = q1[2], fg2 = q1[3];
        const float trHc  = q0[5] + q0[6] + q0[7];
        const float fiLap = q1[5] + q1[6] + q1[7];
        const float jd = -trHc
                         - (cg0 * fg0 + cg1 * fg1 + cg2 * fg2 + c0 * fiLap)
                         + 0.1f * (cg0 + cg1 + cg2);
        const int n = n0 + s;
        out[0 * nB + n]         = c0;
        out[1 * nB + n]         = ct;
        out[2 * nB + 3 * n + 0] = cg0;
        out[2 * nB + 3 * n + 1] = cg1;
        out[2 * nB + 3 * n + 2] = cg2;
        out[5 * nB + n]         = Fi;
        out[6 * nB + 3 * n + 0] = fg0;
        out[6 * nB + 3 * n + 1] = fg1;
        out[6 * nB + 3 * n + 2] = fg2;
        out[9 * nB + n]         = fiLap;
        out[10 * nB + n]        = jd;
    }
}

extern "C" void kernel_launch(void* const* d_in, const int* in_sizes, int n_in,
                              void* d_out, int out_size, void* d_ws, size_t ws_size,
                              hipStream_t stream) {
    const float* x  = (const float*)d_in[0];
    const float* W0 = (const float*)d_in[1];
    const float* b0 = (const float*)d_in[2];
    const float* W1 = (const float*)d_in[3];
    const float* b1 = (const float*)d_in[4];
    const float* W2 = (const float*)d_in[5];
    const float* b2 = (const float*)d_in[6];
    const float* W3 = (const float*)d_in[7];
    const float* b3 = (const float*)d_in[8];
    const float* Wo = (const float*)d_in[9];
    const float* bo = (const float*)d_in[10];
    float* out = (float*)d_out;
    u16*   Wt  = (u16*)d_ws;                 // 3*65536 + 512 bf16 ≈ 385 KB

    const int nB = in_sizes[0] / 4;          // 16384

    hipLaunchKernelGGL(prep_w, dim3(97), dim3(256), 0, stream, W1, W2, W3, Wo, Wt);
    hipLaunchKernelGGL(mlp_jet_mfma, dim3(nB / SPBM), dim3(512), 0, stream,
                       x, W0, b0, b1, b2, b3, bo, Wt, out, nB);
}

// Round 3
// 172.797 us; speedup vs baseline: 1.5150x; 1.5150x over previous
//
#include <hip/hip_runtime.h>

#define HDIM  256
#define YP    264              // padded Y row length in bf16 elems
#define SPBM  8                // samples per block
#define MROWS (SPBM * 8)       // 64 jet rows per block

typedef unsigned short u16;
typedef __attribute__((ext_vector_type(8))) short  short8;   // 8 bf16 (4 VGPRs)
typedef __attribute__((ext_vector_type(4))) float  f32x4;    // MFMA acc

// Row permutation: physical row R for (sample s, channel c):
//   R = 32*(s>>2) + 16*(c>>2) + 4*(s&3) + (c&3)
// => MFMA C-tile pair (2h, 2h+1): lane (g = l>>4) reg j holds
//    acc[2h]  = channels 0..3 (v,g0,g1,g2) of sample 4h+g
//    acc[2h+1]= channels 4..7 (g3,s0,s1,s2) of sample 4h+g
// so the jet nonlinearity is PER-LANE: no cross-lane shuffles in the epilogue.

__device__ __forceinline__ float bf2f(u16 u) {
    union { unsigned int i; float f; } v; v.i = ((unsigned int)u) << 16; return v.f;
}
// cheap round-half-up bf16 (2 VALU instr); fine vs 3% abs threshold
__device__ __forceinline__ u16 f2bf(float f) {
    union { float f; unsigned int u; } v; v.f = f;
    return (u16)((v.u + 0x8000u) >> 16);
}
// proper RNE, used once in prepass for weights
__device__ __forceinline__ u16 f2bf_rne(float f) {
    union { float f; unsigned int u; } v; v.f = f;
    unsigned int r = v.u + 0x7fffu + ((v.u >> 16) & 1u);
    return (u16)(r >> 16);
}
// tanh(x) = 1 - 2/(e^{2x}+1) on raw v_exp_f32 / v_rcp_f32 (~4 instr, NaN-free)
__device__ __forceinline__ float fast_tanh(float x) {
    const float e = __builtin_amdgcn_exp2f(x * 2.885390081777927f); // e^{2x}
    const float r = __builtin_amdgcn_rcpf(e + 1.f);
    return 1.f - 2.f * r;
}

// ---- prepass: LDS-tiled transpose W[k][n] f32 -> Wt[n][k] bf16 (W1,W2,W3),
// ---- plus Wo[k][2] -> Wob[2][256] bf16 at ws + 3*65536.
// 97 blocks (32k x 64n tiles, 32 per matrix).
__global__ __launch_bounds__(256)
void prep_w(const float* __restrict__ W1, const float* __restrict__ W2,
            const float* __restrict__ W3, const float* __restrict__ Wo,
            u16* __restrict__ ws) {
    const int bid = blockIdx.x;
    const int tid = threadIdx.x;
    if (bid == 96) {
#pragma unroll
        for (int oc = 0; oc < 2; ++oc)
            ws[3 * 65536 + oc * 256 + tid] = f2bf_rne(Wo[tid * 2 + oc]);
        return;
    }
    const int which = bid >> 5;          // 0..2
    const int tile  = bid & 31;          // 32 tiles: 8 k-tiles x 4 n-tiles
    const int k0 = (tile & 7) * 32;
    const int n0 = (tile >> 3) * 64;
    const float* W = (which == 0) ? W1 : ((which == 1) ? W2 : W3);
    __shared__ float T[32][65];
    const int rk = tid >> 4;             // 0..15
    const int rn = (tid & 15) * 4;       // 0..60
#pragma unroll
    for (int rep = 0; rep < 2; ++rep) {
        const float4 v = *(const float4*)(W + (k0 + rep * 16 + rk) * 256 + n0 + rn);
        T[rep * 16 + rk][rn + 0] = v.x;
        T[rep * 16 + rk][rn + 1] = v.y;
        T[rep * 16 + rk][rn + 2] = v.z;
        T[rep * 16 + rk][rn + 3] = v.w;
    }
    __syncthreads();
    const int wn = tid >> 2;             // 0..63
    const int wk = (tid & 3) * 8;        // 0,8,16,24
    short8 o;
#pragma unroll
    for (int i = 0; i < 8; ++i)
        o[i] = (short)f2bf_rne(T[wk + i][wn]);
    *(short8*)(ws + which * 65536 + (n0 + wn) * 256 + k0 + wk) = o;
}

// ---- one hidden layer: Y(LDS, 64x256 bf16 jets) @ W(256x256) -> jets, in place ----
// 4 waves: wave wv owns all 64 rows x cols wv*64..+63.
// C/D: col=lane&15, row=(lane>>4)*4+reg.  A: A[m=lane&15][k=8*(lane>>4)+j].
__device__ __forceinline__ void hidden_layer_mfma(u16* __restrict__ Y,
                                                  const u16* __restrict__ Wt,
                                                  const float* __restrict__ b,
                                                  int l, int wv) {
    const int lm    = l & 15;
    const int lk8   = (l >> 4) * 8;
    const int nbase = wv * 64;

    f32x4 acc[4][4];
#pragma unroll
    for (int mt = 0; mt < 4; ++mt)
#pragma unroll
        for (int nt = 0; nt < 4; ++nt) acc[mt][nt] = (f32x4){0.f, 0.f, 0.f, 0.f};

#pragma unroll
    for (int ks = 0; ks < 8; ++ks) {
        const int kk = ks * 32 + lk8;
        short8 a[4], bf[4];
#pragma unroll
        for (int mt = 0; mt < 4; ++mt)
            a[mt] = *(const short8*)(Y + (mt * 16 + lm) * YP + kk);
#pragma unroll
        for (int nt = 0; nt < 4; ++nt)
            bf[nt] = *(const short8*)(Wt + ((nbase + nt * 16 + lm) << 8) + kk);
#pragma unroll
        for (int mt = 0; mt < 4; ++mt)
#pragma unroll
            for (int nt = 0; nt < 4; ++nt)
                acc[mt][nt] = __builtin_amdgcn_mfma_f32_16x16x32_bf16(
                    a[mt], bf[nt], acc[mt][nt], 0, 0, 0);
    }

    float bias[4];
#pragma unroll
    for (int nt = 0; nt < 4; ++nt) bias[nt] = b[nbase + nt * 16 + lm];

    __syncthreads();   // all waves done READING Y before anyone overwrites it

    const int g = l >> 4;    // sample-in-group 0..3
#pragma unroll
    for (int half = 0; half < 2; ++half) {      // samples 4*half+g
#pragma unroll
        for (int nt = 0; nt < 4; ++nt) {
            const f32x4 ulo = acc[2 * half + 0][nt];   // v,g0,g1,g2 preacts
            const f32x4 uhi = acc[2 * half + 1][nt];   // g3,s0,s1,s2 preacts
            const float ty = fast_tanh(ulo[0] + bias[nt]);
            const float t  = 1.f - ty * ty;
            const float m  = -2.f * ty * t;
            const int n = nbase + nt * 16 + lm;
            u16* ylo = Y + (half * 32 + 4 * g) * YP + n;
            u16* yhi = ylo + 16 * YP;
            ylo[0 * YP] = f2bf(ty);
            ylo[1 * YP] = f2bf(t * ulo[1]);
            ylo[2 * YP] = f2bf(t * ulo[2]);
            ylo[3 * YP] = f2bf(t * ulo[3]);
            yhi[0 * YP] = f2bf(t * uhi[0]);
            yhi[1 * YP] = f2bf(t * uhi[1] + m * ulo[1] * ulo[1]);
            yhi[2 * YP] = f2bf(t * uhi[2] + m * ulo[2] * ulo[2]);
            yhi[3 * YP] = f2bf(t * uhi[3] + m * ulo[3] * ulo[3]);
        }
    }
    __syncthreads();
}

__global__ __launch_bounds__(256, 4)
void mlp_jet_mfma(const float* __restrict__ x,
                  const float* __restrict__ W0, const float* __restrict__ b0,
                  const float* __restrict__ b1, const float* __restrict__ b2,
                  const float* __restrict__ b3, const float* __restrict__ bo,
                  const u16* __restrict__ Wt,   // 3 x Wt[n][k] bf16, + Wob[2][256]
                  float* __restrict__ out, int nB) {
    __shared__ __align__(16) u16 Y[MROWS * YP];
    __shared__ float4 xs4[SPBM];
    __shared__ float  part[MROWS][2];

    const int tid = threadIdx.x;
    const int wv  = tid >> 6;            // 0..3
    const int l   = tid & 63;
    const int lm  = l & 15;
    const int lk8 = (l >> 4) * 8;
    const int n0  = blockIdx.x * SPBM;

    // ---- layer 0: 4 -> 256, VALU ----
    if (tid < SPBM) xs4[tid] = *(const float4*)(x + (n0 + tid) * 4);
    __syncthreads();
    {
        const int n = tid;
        const float w0 = W0[0 * HDIM + n], w1 = W0[1 * HDIM + n];
        const float w2 = W0[2 * HDIM + n], w3 = W0[3 * HDIM + n];
        const float bb = b0[n];
#pragma unroll
        for (int s = 0; s < SPBM; ++s) {
            const float4 xv = xs4[s];
            const float u  = xv.x * w0 + xv.y * w1 + xv.z * w2 + xv.w * w3 + bb;
            const float ty = fast_tanh(u);
            const float t  = 1.f - ty * ty;
            const float m  = -2.f * ty * t;
            // permuted rows: base = 32*(s>>2) + 4*(s&3); ch0..3 there, ch4..7 at +16
            u16* ylo = Y + (32 * (s >> 2) + 4 * (s & 3)) * YP + n;
            u16* yhi = ylo + 16 * YP;
            ylo[0 * YP] = f2bf(ty);
            ylo[1 * YP] = f2bf(t * w0);
            ylo[2 * YP] = f2bf(t * w1);
            ylo[3 * YP] = f2bf(t * w2);
            yhi[0 * YP] = f2bf(t * w3);
            yhi[1 * YP] = f2bf(m * w0 * w0);
            yhi[2 * YP] = f2bf(m * w1 * w1);
            yhi[3 * YP] = f2bf(m * w2 * w2);
        }
    }
    __syncthreads();

    // ---- 3 hidden layers on the matrix pipe ----
    hidden_layer_mfma(Y, Wt + 0 * 65536, b1, l, wv);
    hidden_layer_mfma(Y, Wt + 1 * 65536, b2, l, wv);
    hidden_layer_mfma(Y, Wt + 2 * 65536, b3, l, wv);

    // ---- output head on MFMA: wave wv takes physical rows wv*16..wv*16+15 ----
    {
        const u16* wob = Wt + 3 * 65536;
        f32x4 h = (f32x4){0.f, 0.f, 0.f, 0.f};
#pragma unroll
        for (int ks = 0; ks < 8; ++ks) {
            const int kk = ks * 32 + lk8;
            const short8 a = *(const short8*)(Y + (wv * 16 + lm) * YP + kk);
            short8 bfr = (short8){0,0,0,0,0,0,0,0};
            if (lm < 2) bfr = *(const short8*)(wob + lm * 256 + kk);
            h = __builtin_amdgcn_mfma_f32_16x16x32_bf16(a, bfr, h, 0, 0, 0);
        }
        if (lm < 2) {
#pragma unroll
            for (int r = 0; r < 4; ++r)
                part[wv * 16 + (l >> 4) * 4 + r][lm] = h[r];
        }
    }
    __syncthreads();

    if (tid < SPBM) {
        const int s = tid;
        float q0[8], q1[8];
#pragma unroll
        for (int ch = 0; ch < 8; ++ch) {
            const int R = 32 * (s >> 2) + 16 * (ch >> 2) + 4 * (s & 3) + (ch & 3);
            q0[ch] = part[R][0];
            q1[ch] = part[R][1];
        }
        const float c0  = q0[0] + bo[0];
        const float Fi  = q1[0] + bo[1];
        const float cg0 = q0[1], cg1 = q0[2], cg2 = q0[3];
        const float ct  = q0[4];                 // dc/dx_3 (TDIM)
        const float fg0 = q1[1], fg1 = q1[2], fg2 = q1[3];
        const float trHc  = q0[5] + q0[6] + q0[7];
        const float fiLap = q1[5] + q1[6] + q1[7];
        const float jd = -trHc
                         - (cg0 * fg0 + cg1 * fg1 + cg2 * fg2 + c0 * fiLap)
                         + 0.1f * (cg0 + cg1 + cg2);
        const int n = n0 + s;
        out[0 * nB + n]         = c0;
        out[1 * nB + n]         = ct;
        out[2 * nB + 3 * n + 0] = cg0;
        out[2 * nB + 3 * n + 1] = cg1;
        out[2 * nB + 3 * n + 2] = cg2;
        out[5 * nB + n]         = Fi;
        out[6 * nB + 3 * n + 0] = fg0;
        out[6 * nB + 3 * n + 1] = fg1;
        out[6 * nB + 3 * n + 2] = fg2;
        out[9 * nB + n]         = fiLap;
        out[10 * nB + n]        = jd;
    }
}

extern "C" void kernel_launch(void* const* d_in, const int* in_sizes, int n_in,
                              void* d_out, int out_size, void* d_ws, size_t ws_size,
                              hipStream_t stream) {
    const float* x  = (const float*)d_in[0];
    const float* W0 = (const float*)d_in[1];
    const float* b0 = (const float*)d_in[2];
    const float* W1 = (const float*)d_in[3];
    const float* b1 = (const float*)d_in[4];
    const float* W2 = (const float*)d_in[5];
    const float* b2 = (const float*)d_in[6];
    const float* W3 = (const float*)d_in[7];
    const float* b3 = (const float*)d_in[8];
    const float* Wo = (const float*)d_in[9];
    const float* bo = (const float*)d_in[10];
    float* out = (float*)d_out;
    u16*   Wt  = (u16*)d_ws;                 // 3*65536 + 512 bf16 ≈ 385 KB

    const int nB = in_sizes[0] / 4;          // 16384

    hipLaunchKernelGGL(prep_w, dim3(97), dim3(256), 0, stream, W1, W2, W3, Wo, Wt);
    hipLaunchKernelGGL(mlp_jet_mfma, dim3(nB / SPBM), dim3(256), 0, stream,
                       x, W0, b0, b1, b2, b3, bo, Wt, out, nB);
}